// Round 8
// baseline (968.548 us; speedup 1.0000x reference)
//
#include <hip/hip_runtime.h>
#include <stdint.h>

#define H_ 16
#define DH_ 128
#define RK_ 512
#define RD_ 64
#define B_ 2
#define L_ 2048
#define E_ 2048
#define DQ_ 192            // DH+RD
#define NQ_ (H_*DQ_)       // 3072
#define NKV_ 576
#define QKVP_ 3840         // fused q/kv projection width, padded to 15*256
#define NUP_ (H_*(2*DH_+RD_)) // 5120
#define M_ (B_*L_)         // 4096

typedef unsigned short u16;
typedef __bf16 bf16x8 __attribute__((ext_vector_type(8)));
typedef float floatx4 __attribute__((ext_vector_type(4)));

__device__ __forceinline__ u16 f2bf(float f) {
    union { float f; uint32_t u; } v; v.f = f;
    uint32_t u = v.u;
    u = (u + 0x7fffu + ((u >> 16) & 1u)) >> 16;
    return (u16)u;
}
__device__ __forceinline__ float bf2f(u16 b) {
    union { uint32_t u; float f; } v; v.u = ((uint32_t)b) << 16; return v.f;
}
// pack two f32 -> two bf16 (RNE), one instruction
__device__ __forceinline__ uint32_t cvtpk(float lo, float hi) {
    uint32_t r;
    asm("v_cvt_pk_bf16_f32 %0, %1, %2" : "=v"(r) : "v"(lo), "v"(hi));
    return r;
}

__device__ __forceinline__ void gld_lds16(const void* g, void* l) {
    __builtin_amdgcn_global_load_lds((__attribute__((address_space(1))) void*)(g),
                                     (__attribute__((address_space(3))) void*)(l),
                                     16, 0, 0);
}

// ---------------- fp32 -> bf16 elementwise (x) ----------------
__global__ void convert_bf16(const float* __restrict__ in, u16* __restrict__ out, int n4) {
    int i = blockIdx.x * blockDim.x + threadIdx.x;
    if (i >= n4) return;
    float4 v = ((const float4*)in)[i];
    uint2 o;
    o.x = cvtpk(v.x, v.y);
    o.y = cvtpk(v.z, v.w);
    ((uint2*)out)[i] = o;
}

// ---------------- all 4 weight transposes in ONE launch ----------------
__global__ void transpose_all(const float* __restrict__ wq, const float* __restrict__ wkv,
                              const float* __restrict__ wup, const float* __restrict__ wout,
                              u16* __restrict__ wqkvT, u16* __restrict__ wupT,
                              u16* __restrict__ woutT) {
    __shared__ float tile[32][33];
    int bid = blockIdx.x;
    const float* W; u16* Wt; int K, N, bx, by;
    if (bid < 6144)        { W = wq;   Wt = wqkvT;                      K = 2048; N = 3072; bx = bid % 96;  by = bid / 96; }
    else if (bid < 7680)   { int b = bid - 6144; W = wkv;  Wt = wqkvT + (size_t)3072 * 2048; K = 2048; N = 576;  bx = b % 24;  by = b / 24; }
    else if (bid < 10240)  { int b = bid - 7680; W = wup;  Wt = wupT;   K = 512;  N = 5120; bx = b % 160; by = b / 160; }
    else                   { int b = bid - 10240; W = wout; Wt = woutT; K = 3072; N = 2048; bx = b % 64;  by = b / 64; }
    int n0 = bx * 32, k0 = by * 32;
    int tx = threadIdx.x, ty = threadIdx.y; // 32 x 8
    for (int i = 0; i < 4; i++) {
        int k = k0 + ty + i * 8, n = n0 + tx;
        tile[ty + i * 8][tx] = (n < N) ? W[(size_t)k * N + n] : 0.f;
    }
    __syncthreads();
    for (int i = 0; i < 4; i++) {
        int n = n0 + ty + i * 8, k = k0 + tx;
        Wt[(size_t)n * K + k] = f2bf(tile[tx][ty + i * 8]);
    }
}

// ---------------- 256x128 GEMM, BK=32, TRIPLE-buffered LDS, counted vmcnt ----------------
template<bool BF16OUT>
__global__ __launch_bounds__(512, 4) void gemm256(const u16* __restrict__ A,
                                                  const u16* __restrict__ Bt,
                                                  void* __restrict__ Cv,
                                                  int M, int N, int K, int lda) {
    __shared__ __align__(16) u16 As[3][256 * 32];
    __shared__ __align__(16) u16 Bs[3][128 * 32];
    const int tid = threadIdx.x;
    const int wave = tid >> 6, lane = tid & 63;
    const int quad = lane >> 4, l16 = lane & 15;
    const int wm = (wave >> 1) * 64, wn = (wave & 1) * 64;

    // XCD-aware bijective swizzle (m204), bx-major: consecutive wg share B-panel
    int nwg = gridDim.x * gridDim.y;
    int flat = blockIdx.y * gridDim.x + blockIdx.x;
    int q = nwg >> 3, r = nwg & 7;
    int xcd = flat & 7, pos = flat >> 3;
    int wg = (xcd < r) ? xcd * (q + 1) + pos : r * (q + 1) + (xcd - r) * q + pos;
    const int m0 = (wg & 15) * 256;          // gridDim.y == 16 (M = 4096)
    const int n0 = (wg >> 4) * 128;

    const u16* Ab = A + (size_t)m0 * lda;
    const u16* Bb = Bt + (size_t)n0 * K;

    const int qsw = (quad ^ ((l16 >> 1) & 3)) * 8;   // swizzled read offset

    floatx4 zero4 = {0.f, 0.f, 0.f, 0.f};
    floatx4 acc[4][4];
#pragma unroll
    for (int i = 0; i < 4; i++)
#pragma unroll
        for (int j = 0; j < 4; j++) acc[i][j] = zero4;

    auto stage = [&](int t, int b) {
        const u16* Ak = Ab + t * 32;
        const u16* Bk = Bb + t * 32;
#pragma unroll
        for (int it = 0; it < 2; ++it) {             // A: 256 rows x 4 blocks
            int c = it * 512 + tid;
            int row = c >> 2, blk = c & 3;
            int bg = blk ^ ((row >> 1) & 3);
            gld_lds16(Ak + (size_t)row * lda + bg * 8, As[b] + row * 32 + blk * 8);
        }
        {                                             // B: 128 rows x 4 blocks
            int row = tid >> 2, blk = tid & 3;
            int bg = blk ^ ((row >> 1) & 3);
            gld_lds16(Bk + (size_t)row * K + bg * 8, Bs[b] + row * 32 + blk * 8);
        }
    };

    const int NT = K >> 5;
    stage(0, 0);
    stage(1, 1);
    int rb = 0;
    for (int t = 0; t < NT; ++t) {
        if (t + 2 < NT) {
            stage(t + 2, rb ? rb - 1 : 2);   // (rb+2)%3: buffer retired at t-1
            asm volatile("s_waitcnt vmcnt(6)" ::: "memory");   // oldest 3 (= tile t) done
        } else if (t + 1 < NT) {
            asm volatile("s_waitcnt vmcnt(3)" ::: "memory");
        } else {
            asm volatile("s_waitcnt vmcnt(0)" ::: "memory");
        }
        __builtin_amdgcn_s_barrier();        // all waves' tile-t loads landed

        const u16* Ar = As[rb];
        const u16* Br = Bs[rb];
        bf16x8 af[4], bfv[4];
#pragma unroll
        for (int i = 0; i < 4; i++) af[i]  = *(const bf16x8*)(Ar + (wm + i * 16 + l16) * 32 + qsw);
#pragma unroll
        for (int j = 0; j < 4; j++) bfv[j] = *(const bf16x8*)(Br + (wn + j * 16 + l16) * 32 + qsw);
        __builtin_amdgcn_s_setprio(1);
#pragma unroll
        for (int i = 0; i < 4; i++)
#pragma unroll
            for (int j = 0; j < 4; j++)
                acc[i][j] = __builtin_amdgcn_mfma_f32_16x16x32_bf16(af[i], bfv[j], acc[i][j], 0, 0, 0);
        __builtin_amdgcn_s_setprio(0);
        __builtin_amdgcn_s_barrier();        // buf[rb] fully read -> may be restaged
        rb = (rb == 2) ? 0 : rb + 1;
    }

#pragma unroll
    for (int i = 0; i < 4; i++)
#pragma unroll
        for (int j = 0; j < 4; j++) {
            int mrow = m0 + wm + i * 16 + quad * 4;
            int ncol = n0 + wn + j * 16 + l16;
            if (BF16OUT) {
                u16* Cp = (u16*)Cv + (size_t)mrow * N + ncol;
                for (int rr = 0; rr < 4; rr++) Cp[(size_t)rr * N] = f2bf(acc[i][j][rr]);
            } else {
                float* Cp = (float*)Cv + (size_t)mrow * N + ncol;
                for (int rr = 0; rr < 4; rr++) Cp[(size_t)rr * N] = acc[i][j][rr];
            }
        }
}

// ---------------- fused build_q + k_rope from bf16 qkv ----------------
__global__ void build_qckv(const u16* __restrict__ qkv, const float* __restrict__ cosT,
                           const float* __restrict__ sinT, u16* __restrict__ qb,
                           u16* __restrict__ kropeb) {
    const float QS = 0.07216878364870323f * 1.4426950408889634f; // 1/sqrt(192) * log2(e)
    int idx = blockIdx.x * blockDim.x + threadIdx.x;
    const int NQTH = M_ * H_ * 96;
    if (idx < NQTH) {
        int p = idx % 96; int t = idx / 96; int h = t % H_; int row = t / H_;
        int l = row & (L_ - 1); int b = row >> 11;
        const u16* src = qkv + (size_t)row * QKVP_ + h * DQ_;
        u16* dst = qb + ((size_t)(b * H_ + h) * L_ + l) * DQ_;
        int d = 2 * p;
        uint32_t w = *(const uint32_t*)(src + d);
        float x1 = bf2f((u16)(w & 0xffff)), x2 = bf2f((u16)(w >> 16));
        uint32_t o;
        if (d < DH_) o = cvtpk(x1 * QS, x2 * QS);
        else {
            int i = (d - DH_) >> 1;
            float c = cosT[(size_t)l * 32 + i], s = sinT[(size_t)l * 32 + i];
            o = cvtpk((x1 * c - x2 * s) * QS, (x1 * s + x2 * c) * QS);
        }
        *(uint32_t*)(dst + d) = o;
    } else {
        idx -= NQTH;
        if (idx >= M_ * 32) return;
        int i = idx & 31; int row = idx >> 5;
        int l = row & (L_ - 1);
        uint32_t w = *(const uint32_t*)(qkv + (size_t)row * QKVP_ + NQ_ + RK_ + 2 * i);
        float x1 = bf2f((u16)(w & 0xffff)), x2 = bf2f((u16)(w >> 16));
        float c = cosT[(size_t)l * 32 + i], s = sinT[(size_t)l * 32 + i];
        *(uint32_t*)(kropeb + (size_t)row * RD_ + 2 * i) = cvtpk(x1 * c - x2 * s, x1 * s + x2 * c);
    }
}

// ---------------- build k (B,H,L,192) + vT (B,H,192,L perm) from bf16 up ----------------
__global__ __launch_bounds__(256) void build_kvt(const u16* __restrict__ up,
        const u16* __restrict__ kropeb, u16* __restrict__ kb, u16* __restrict__ vtb) {
    __shared__ u16 vt[64][193];
    int blk = blockIdx.x;          // (b*H+h)*32 + lt
    int lt = blk & 31; int bh = blk >> 5; int h = bh % H_; int b = bh / H_;
    int tid = threadIdx.x;
    int l0 = lt * 64;
    for (int it = 0; it < 48; ++it) {
        int idx = it * 256 + tid;  // 64*192
        int lr = idx / 192, d = idx % 192;
        size_t row = (size_t)b * L_ + l0 + lr;
        u16 vv = (d < DH_) ? up[row * NUP_ + h * 320 + DH_ + d]
                           : up[row * NUP_ + h * 320 + 2 * DH_ + (d - DH_)];
        vt[lr][d] = vv;
        u16 kbf = (d < DH_) ? up[row * NUP_ + h * 320 + d]
                            : kropeb[row * RD_ + (d - DH_)];
        kb[((size_t)bh * L_ + l0 + lr) * DQ_ + d] = kbf;
    }
    __syncthreads();
    for (int it = 0; it < 48; ++it) {
        int idx = it * 256 + tid;
        int lr = idx & 63, d = idx >> 6;
        int l = l0 + lr;
        int s5 = l & 31;
        int k5 = ((s5 >> 2) & 3) * 8 + ((s5 >> 4) & 1) * 4 + (s5 & 3);
        int lp = (l & ~31) | k5;
        vtb[((size_t)bh * DQ_ + d) * L_ + lp] = vt[lr][d];
    }
}

// ---------------- flash attention, causal, S^T, 512 blocks x 512 threads ----------------
// 4-way split-s: block (bh, t, j): segs QT=7-t then QT=t, quarter j of each QT's
// tile range [0, 4QT+3] -> (8-t)+(t+1) = 9 iters/block, perfectly balanced.
// LDS 72KB (K dbuf 2x24K + V single 24K) + launch_bounds(512,4) -> 2 blocks/CU:
// the co-resident block fills this block's barrier/dependency holes (TLP fix).
// Iter: issue V(st)+K(st+1) -> QK^T+softmax (V latency hides) -> vmcnt(3)+bar
// -> PV -> vmcnt(0)+bar (K(st+1) had the whole iter to land).
__global__ __launch_bounds__(512, 4) void attn(const u16* __restrict__ qb,
        const u16* __restrict__ kb, const u16* __restrict__ vtb,
        u16* __restrict__ poA, u16* __restrict__ poS,
        float* __restrict__ pmB, float* __restrict__ plB) {
    __shared__ __align__(16) u16 Ks[2][64 * 192];
    __shared__ __align__(16) u16 Vs[192 * 64];
    int id = blockIdx.x;
    int bh = id & 31, tj = id >> 5;      // same-bh blocks share XCD (id%8 = bh%8)
    int t = tj >> 2, j = tj & 3;
    int tid = threadIdx.x, wave = tid >> 6, lane = tid & 63;
    int quad = lane >> 4, l16 = lane & 15;

    // swizzle lane constants: row&7 == l16&7 for all fragment reads
    const int x7 = l16 & 7;
    const int h2 = (x7 >> 2) & 1;
    const int qx = quad ^ (x7 & 3);
    const int oA = h2 * 32 + qx * 8;        // even kk  / V g=0
    const int oB = (1 - h2) * 32 + qx * 8;  // odd  kk  / V g=1

    const size_t poSzE = (size_t)256 * 256 * 192;   // elements per split
    u16* po = (j == 0) ? poA : poS + (size_t)(j - 1) * poSzE;
    float* pm = pmB + (size_t)j * 65536;
    float* pl = plB + (size_t)j * 65536;

    const u16* kbase0 = kb + (size_t)bh * L_ * DQ_;
    const u16* vbase0 = vtb + (size_t)bh * (size_t)DQ_ * L_;
    floatx4 zero4 = {0.f, 0.f, 0.f, 0.f};

    auto stageK = [&](int st, int buf) {
        const u16* kg = kbase0 + (size_t)st * 64 * DQ_;
        u16* kd = &Ks[buf][0];
        for (int it = 0; it < 3; ++it) {
            int c = it * 512 + tid;          // 0..1535 = 64 rows * 24 blocks
            int s = c / 24, blk = c - s * 24;
            int blog = (blk & 24) | ((blk & 7) ^ (s & 7));
            gld_lds16(kg + (size_t)s * DQ_ + blog * 8, kd + c * 8);
        }
    };
    auto stageV = [&](int st) {
        const u16* vg = vbase0 + st * 64;
        for (int it = 0; it < 3; ++it) {
            int c = it * 512 + tid;          // 0..1535 = 192 rows * 8 blocks
            int d = c >> 3, blk = c & 7;
            int blog = blk ^ (d & 7);
            gld_lds16(vg + (size_t)d * L_ + blog * 8, Vs + c * 8);
        }
    };

    for (int seg = 0; seg < 2; ++seg) {
        const int QT = seg == 0 ? (7 - t) : t;
        const int st0 = j * (QT + 1);
        const int st1 = st0 + QT;

        bf16x8 aq[2][6];
        const u16* qbase = qb + ((size_t)bh * L_ + QT * 256 + wave * 16 + l16) * DQ_;
        for (int a = 0; a < 2; a++)
            for (int kk = 0; kk < 6; kk++)
                aq[a][kk] = *(const bf16x8*)(qbase + a * 128 * DQ_ + kk * 32 + quad * 8);

        floatx4 o[2][12];
        for (int a = 0; a < 2; a++) for (int i = 0; i < 12; i++) o[a][i] = zero4;
        float m_i[2] = {-INFINITY, -INFINITY};
        float l_i[2] = {0.f, 0.f};

        int cur = 0;
        stageK(st0, 0);                                     // prologue
        asm volatile("s_waitcnt vmcnt(0)" ::: "memory");
        __builtin_amdgcn_s_barrier();

        for (int st = st0; st <= st1; ++st) {
            stageV(st);                                      // 3 loads (oldest)
            if (st < st1) stageK(st + 1, cur ^ 1);           // +3 loads
            const u16* Kc = &Ks[cur][0];

            // liveness: R multiple of 16; rowset live iff R >= 0
            int R0 = QT * 256 + wave * 16 - st * 64;
            int R1 = R0 + 128;
            int smax0 = min(3, (R0 + 15) >> 4);
            int smax1 = min(3, (R1 + 15) >> 4);
            bool live0 = smax0 >= 0, live1 = smax1 >= 0;

            float pv[2][4][4];
            float mxa[2] = {-INFINITY, -INFINITY};
#pragma unroll
            for (int stile = 0; stile < 4; ++stile) {
                if (stile > smax1) {
                    for (int r = 0; r < 4; r++) { pv[0][stile][r] = 0.f; pv[1][stile][r] = 0.f; }
                    continue;
                }
                bool do0 = (stile <= smax0);
                floatx4 s1v = zero4, s0v = zero4;
#pragma unroll
                for (int kk = 0; kk < 6; kk++) {
                    int off = (kk >> 1) * 64 + ((kk & 1) ? oB : oA);
                    bf16x8 kf = *(const bf16x8*)(Kc + (stile * 16 + l16) * 192 + off);
                    s1v = __builtin_amdgcn_mfma_f32_16x16x32_bf16(kf, aq[1][kk], s1v, 0, 0, 0);
                    if (do0) s0v = __builtin_amdgcn_mfma_f32_16x16x32_bf16(kf, aq[0][kk], s0v, 0, 0, 0);
                }
                int sb = stile * 16;
                if (sb + 15 > R1) {
                    for (int r = 0; r < 4; r++) {
                        float v = (sb + quad * 4 + r > R1 + l16) ? -1e30f : s1v[r];
                        pv[1][stile][r] = v; mxa[1] = fmaxf(mxa[1], v);
                    }
                } else {
                    for (int r = 0; r < 4; r++) { pv[1][stile][r] = s1v[r]; mxa[1] = fmaxf(mxa[1], s1v[r]); }
                }
                if (do0) {
                    if (sb + 15 > R0) {
                        for (int r = 0; r < 4; r++) {
                            float v = (sb + quad * 4 + r > R0 + l16) ? -1e30f : s0v[r];
                            pv[0][stile][r] = v; mxa[0] = fmaxf(mxa[0], v);
                        }
                    } else {
                        for (int r = 0; r < 4; r++) { pv[0][stile][r] = s0v[r]; mxa[0] = fmaxf(mxa[0], s0v[r]); }
                    }
                } else {
                    for (int r = 0; r < 4; r++) pv[0][stile][r] = 0.f;
                }
            }

            bf16x8 pf[2][2];
            bool lv[2] = {live0, live1};
            int smx[2] = {smax0, smax1};
#pragma unroll
            for (int a = 0; a < 2; a++) {
                if (!lv[a]) continue;
                float mx = mxa[a];
                mx = fmaxf(mx, __shfl_xor(mx, 16));
                mx = fmaxf(mx, __shfl_xor(mx, 32));
                float mn;
                if (__all(mx <= m_i[a] + 8.0f)) {
                    mn = m_i[a];                 // defer-max: keep stale max, no rescale
                } else {
                    mn = fmaxf(m_i[a], mx);
                    float alpha = exp2f(m_i[a] - mn);
                    m_i[a] = mn;
                    l_i[a] *= alpha;
                    for (int i = 0; i < 12; i++) o[a][i] *= alpha;
                }
                float rs = 0.f;
#pragma unroll
                for (int stile = 0; stile < 4; ++stile) {
                    if (stile > smx[a]) continue;
                    for (int r = 0; r < 4; r++) {
                        float e = exp2f(pv[a][stile][r] - mn);
                        pv[a][stile][r] = e;
                        rs += e;
                    }
                }
                rs += __shfl_xor(rs, 16);
                rs += __shfl_xor(rs, 32);
                l_i[a] += rs;
                for (int g = 0; g < 2; g++) {
                    union { bf16x8 v; u16 s[8]; } u;
                    for (int r = 0; r < 4; r++) {
                        u.s[r]     = f2bf(pv[a][g * 2][r]);
                        u.s[4 + r] = f2bf(pv[a][g * 2 + 1][r]);
                    }
                    pf[a][g] = u.v;
                }
            }

            // V(st) landed: own-wave counted wait + barrier publishes to all waves
            if (st < st1) { asm volatile("s_waitcnt vmcnt(3)" ::: "memory"); }
            else          { asm volatile("s_waitcnt vmcnt(0)" ::: "memory"); }
            __builtin_amdgcn_s_barrier();

            for (int g = 0; g < 2; g++) {
                int vo = g ? oB : oA;
#pragma unroll
                for (int dtile = 0; dtile < 12; dtile++) {
                    bf16x8 vf = *(const bf16x8*)(Vs + (dtile * 16 + l16) * 64 + vo);
                    if (live0)
                        o[0][dtile] = __builtin_amdgcn_mfma_f32_16x16x32_bf16(vf, pf[0][g], o[0][dtile], 0, 0, 0);
                    if (live1)
                        o[1][dtile] = __builtin_amdgcn_mfma_f32_16x16x32_bf16(vf, pf[1][g], o[1][dtile], 0, 0, 0);
                }
            }
            asm volatile("s_waitcnt vmcnt(0)" ::: "memory");   // K(st+1) landed (had full iter)
            __builtin_amdgcn_s_barrier();                      // Vs/Ks WAR + K publish
            cur ^= 1;
        }

        // write partials: po[tile][q 256][d 192] bf16, pm/pl[tile][q 256]
        int tile = bh * 8 + QT;
        for (int a = 0; a < 2; a++) {
            int q = a * 128 + wave * 16 + l16;
            u16* dst = po + ((size_t)tile * 256 + q) * 192;
            for (int dtile = 0; dtile < 12; dtile++) {
                ushort4 pk;
                pk.x = f2bf(o[a][dtile][0]);
                pk.y = f2bf(o[a][dtile][1]);
                pk.z = f2bf(o[a][dtile][2]);
                pk.w = f2bf(o[a][dtile][3]);
                *(ushort4*)(dst + dtile * 16 + quad * 4) = pk;
            }
            if (quad == 0) {
                pm[(size_t)tile * 256 + q] = m_i[a];
                pl[(size_t)tile * 256 + q] = l_i[a];
            }
        }
        __syncthreads();
    }
}

// ---------------- merge the four split-s quarters -> ao (B,L,H,192) bf16 ----------------
__global__ void attn_merge(const u16* __restrict__ poA, const u16* __restrict__ poS,
                           const float* __restrict__ pmB, const float* __restrict__ plB,
                           u16* __restrict__ ao) {
    int idx = blockIdx.x * blockDim.x + threadIdx.x;   // 256*256*48
    int c = idx % 48; int rest = idx / 48;
    int q = rest & 255; int tile = rest >> 8;
    int bh = tile >> 3, QT = tile & 7;
    size_t mi = (size_t)tile * 256 + q;
    const size_t poSzE = (size_t)256 * 256 * 192;
    float mj[4], lj[4];
    float m = -INFINITY;
    for (int jj = 0; jj < 4; jj++) {
        mj[jj] = pmB[(size_t)jj * 65536 + mi];
        lj[jj] = plB[(size_t)jj * 65536 + mi];
        m = fmaxf(m, mj[jj]);
    }
    float aj[4], denom = 0.f;
    for (int jj = 0; jj < 4; jj++) { aj[jj] = exp2f(mj[jj] - m); denom += lj[jj] * aj[jj]; }
    float inv = 1.0f / denom;
    float acc0 = 0.f, acc1 = 0.f, acc2 = 0.f, acc3 = 0.f;
    for (int jj = 0; jj < 4; jj++) {
        const u16* pj = (jj == 0) ? poA : poS + (size_t)(jj - 1) * poSzE;
        ushort4 u0 = *(const ushort4*)(pj + mi * 192 + c * 4);
        float s = aj[jj] * inv;
        acc0 += bf2f(u0.x) * s; acc1 += bf2f(u0.y) * s;
        acc2 += bf2f(u0.z) * s; acc3 += bf2f(u0.w) * s;
    }
    int b = bh >> 4, h = bh & 15;
    int l = QT * 256 + q;
    u16* dst = ao + (((size_t)(b * L_ + l)) * H_ + h) * DQ_ + c * 4;
    uint2 pk2;
    pk2.x = cvtpk(acc0, acc1);
    pk2.y = cvtpk(acc2, acc3);
    *(uint2*)dst = pk2;
}

extern "C" void kernel_launch(void* const* d_in, const int* in_sizes, int n_in,
                              void* d_out, int out_size, void* d_ws, size_t ws_size,
                              hipStream_t stream) {
    const float* x    = (const float*)d_in[0];
    const float* cosT = (const float*)d_in[1];
    const float* sinT = (const float*)d_in[2];
    const float* wq   = (const float*)d_in[3];
    const float* wkv  = (const float*)d_in[4];
    const float* wup  = (const float*)d_in[5];
    const float* wout = (const float*)d_in[6];
    float* out = (float*)d_out;
    char* ws = (char*)d_ws;

    size_t off = 0;
    auto alloc = [&](size_t b) { size_t r = off; off += (b + 255) & ~(size_t)255; return r; };
    u16* xb     = (u16*)(ws + alloc((size_t)M_ * E_ * 2));      // 16.78 MB  (dead after qkv GEMM)
    u16* wqkvT  = (u16*)(ws + alloc((size_t)QKVP_ * E_ * 2));   // 15.73 MB  (dead after qkv GEMM)
    u16* wupT   = (u16*)(ws + alloc((size_t)NUP_ * RK_ * 2));
    u16* woutT  = (u16*)(ws + alloc((size_t)E_ * NQ_ * 2));
    u16* qb     = (u16*)(ws + alloc((size_t)B_ * H_ * L_ * DQ_ * 2));
    u16* kb     = (u16*)(ws + alloc((size_t)B_ * H_ * L_ * DQ_ * 2));
    u16* vtb    = (u16*)(ws + alloc((size_t)B_ * H_ * DQ_ * L_ * 2));
    u16* ao     = (u16*)(ws + alloc((size_t)M_ * NQ_ * 2));
    u16* kropeb = (u16*)(ws + alloc((size_t)M_ * RD_ * 2));
    char* scratch = ws + alloc((size_t)M_ * NUP_ * 4);   // 83.9 MB union region
    // phase 1: bf16 intermediates qkvb [M x 3840] then upb [M x 5120] (no alias)
    u16* qkvb = (u16*)(scratch);                                  // 31.5 MB
    size_t qkvSz = ((size_t)M_ * QKVP_ * 2 + 255) & ~(size_t)255;
    u16* upb  = (u16*)(scratch + qkvSz);                          // 41.9 MB (total 73.4 < 83.9)
    // phase 2 (attn): 4 partial buffers. po j=0 overlays dead xb+wqkvT (25.2 <= 32.5 MB);
    // j=1..3 + pm/pl in scratch: 3*25.2 + 2.0 = 77.6 MB <= 83.9.
    size_t poSz = (size_t)256 * 256 * 192 * 2;                    // 25.2 MB
    u16*   poA = (u16*)(ws);
    u16*   poS = (u16*)(scratch);
    float* pmB = (float*)(scratch + 3 * poSz);                    // [4][65536]
    float* plB = (float*)(scratch + 3 * poSz + 4 * 65536 * 4);

    dim3 tb(32, 8);
    int n4 = M_ * E_ / 4;
    convert_bf16<<<(n4 + 255) / 256, 256, 0, stream>>>(x, xb, n4);
    transpose_all<<<16384, tb, 0, stream>>>(wq, wkv, wup, wout, wqkvT, wupT, woutT);

    // fused q+kv projection: 256x128 GEMM, bf16 out, grid 30x16 = 480 blocks
    gemm256<true><<<dim3(QKVP_ / 128, M_ / 256), 512, 0, stream>>>(xb, wqkvT, qkvb, M_, QKVP_, E_, E_);

    int nb = (M_ * H_ * 96 + M_ * 32 + 255) / 256;
    build_qckv<<<nb, 256, 0, stream>>>(qkvb, cosT, sinT, qb, kropeb);

    // up-projection: A = qkvb cols 3072..3583 (lda=3840), bf16 out, grid 40x16
    gemm256<true><<<dim3(NUP_ / 128, M_ / 256), 512, 0, stream>>>(qkvb + NQ_, wupT, upb, M_, NUP_, RK_, QKVP_);
    build_kvt<<<B_ * H_ * 32, 256, 0, stream>>>(upb, kropeb, kb, vtb);

    attn<<<512, 512, 0, stream>>>(qb, kb, vtb, poA, poS, pmB, plB);
    attn_merge<<<(256 * 256 * 48) / 256, 256, 0, stream>>>(poA, poS, pmB, plB, ao);

    // output projection: 256x128 GEMM, fp32 out, grid 16x16 = 256 blocks
    gemm256<false><<<dim3(E_ / 128, M_ / 256), 512, 0, stream>>>(ao, woutT, out, M_, E_, NQ_, NQ_);
}

// Round 9
// 542.186 us; speedup vs baseline: 1.7864x; 1.7864x over previous
//
#include <hip/hip_runtime.h>
#include <stdint.h>

#define H_ 16
#define DH_ 128
#define RK_ 512
#define RD_ 64
#define B_ 2
#define L_ 2048
#define E_ 2048
#define DQ_ 192            // DH+RD
#define NQ_ (H_*DQ_)       // 3072
#define NKV_ 576
#define QKVP_ 3840         // fused q/kv projection width, padded to 15*256
#define NUP_ (H_*(2*DH_+RD_)) // 5120
#define M_ (B_*L_)         // 4096

typedef unsigned short u16;
typedef __bf16 bf16x8 __attribute__((ext_vector_type(8)));
typedef float floatx4 __attribute__((ext_vector_type(4)));

__device__ __forceinline__ u16 f2bf(float f) {
    union { float f; uint32_t u; } v; v.f = f;
    uint32_t u = v.u;
    u = (u + 0x7fffu + ((u >> 16) & 1u)) >> 16;
    return (u16)u;
}
__device__ __forceinline__ float bf2f(u16 b) {
    union { uint32_t u; float f; } v; v.u = ((uint32_t)b) << 16; return v.f;
}
// pack two f32 -> two bf16 (RNE), one instruction
__device__ __forceinline__ uint32_t cvtpk(float lo, float hi) {
    uint32_t r;
    asm("v_cvt_pk_bf16_f32 %0, %1, %2" : "=v"(r) : "v"(lo), "v"(hi));
    return r;
}

__device__ __forceinline__ void gld_lds16(const void* g, void* l) {
    __builtin_amdgcn_global_load_lds((__attribute__((address_space(1))) void*)(g),
                                     (__attribute__((address_space(3))) void*)(l),
                                     16, 0, 0);
}

// ---------------- fp32 -> bf16 elementwise (x) ----------------
__global__ void convert_bf16(const float* __restrict__ in, u16* __restrict__ out, int n4) {
    int i = blockIdx.x * blockDim.x + threadIdx.x;
    if (i >= n4) return;
    float4 v = ((const float4*)in)[i];
    uint2 o;
    o.x = cvtpk(v.x, v.y);
    o.y = cvtpk(v.z, v.w);
    ((uint2*)out)[i] = o;
}

// ---------------- all 4 weight transposes in ONE launch ----------------
__global__ void transpose_all(const float* __restrict__ wq, const float* __restrict__ wkv,
                              const float* __restrict__ wup, const float* __restrict__ wout,
                              u16* __restrict__ wqkvT, u16* __restrict__ wupT,
                              u16* __restrict__ woutT) {
    __shared__ float tile[32][33];
    int bid = blockIdx.x;
    const float* W; u16* Wt; int K, N, bx, by;
    if (bid < 6144)        { W = wq;   Wt = wqkvT;                      K = 2048; N = 3072; bx = bid % 96;  by = bid / 96; }
    else if (bid < 7680)   { int b = bid - 6144; W = wkv;  Wt = wqkvT + (size_t)3072 * 2048; K = 2048; N = 576;  bx = b % 24;  by = b / 24; }
    else if (bid < 10240)  { int b = bid - 7680; W = wup;  Wt = wupT;   K = 512;  N = 5120; bx = b % 160; by = b / 160; }
    else                   { int b = bid - 10240; W = wout; Wt = woutT; K = 3072; N = 2048; bx = b % 64;  by = b / 64; }
    int n0 = bx * 32, k0 = by * 32;
    int tx = threadIdx.x, ty = threadIdx.y; // 32 x 8
    for (int i = 0; i < 4; i++) {
        int k = k0 + ty + i * 8, n = n0 + tx;
        tile[ty + i * 8][tx] = (n < N) ? W[(size_t)k * N + n] : 0.f;
    }
    __syncthreads();
    for (int i = 0; i < 4; i++) {
        int n = n0 + ty + i * 8, k = k0 + tx;
        Wt[(size_t)n * K + k] = f2bf(tile[tx][ty + i * 8]);
    }
}

// ---------------- 256x128 GEMM, BK=32, TRIPLE-buffered LDS, counted vmcnt ----------------
template<bool BF16OUT>
__global__ __launch_bounds__(512, 4) void gemm256(const u16* __restrict__ A,
                                                  const u16* __restrict__ Bt,
                                                  void* __restrict__ Cv,
                                                  int M, int N, int K, int lda) {
    __shared__ __align__(16) u16 As[3][256 * 32];
    __shared__ __align__(16) u16 Bs[3][128 * 32];
    const int tid = threadIdx.x;
    const int wave = tid >> 6, lane = tid & 63;
    const int quad = lane >> 4, l16 = lane & 15;
    const int wm = (wave >> 1) * 64, wn = (wave & 1) * 64;

    // XCD-aware bijective swizzle (m204), bx-major: consecutive wg share B-panel
    int nwg = gridDim.x * gridDim.y;
    int flat = blockIdx.y * gridDim.x + blockIdx.x;
    int q = nwg >> 3, r = nwg & 7;
    int xcd = flat & 7, pos = flat >> 3;
    int wg = (xcd < r) ? xcd * (q + 1) + pos : r * (q + 1) + (xcd - r) * q + pos;
    const int m0 = (wg & 15) * 256;          // gridDim.y == 16 (M = 4096)
    const int n0 = (wg >> 4) * 128;

    const u16* Ab = A + (size_t)m0 * lda;
    const u16* Bb = Bt + (size_t)n0 * K;

    const int qsw = (quad ^ ((l16 >> 1) & 3)) * 8;   // swizzled read offset

    floatx4 zero4 = {0.f, 0.f, 0.f, 0.f};
    floatx4 acc[4][4];
#pragma unroll
    for (int i = 0; i < 4; i++)
#pragma unroll
        for (int j = 0; j < 4; j++) acc[i][j] = zero4;

    auto stage = [&](int t, int b) {
        const u16* Ak = Ab + t * 32;
        const u16* Bk = Bb + t * 32;
#pragma unroll
        for (int it = 0; it < 2; ++it) {             // A: 256 rows x 4 blocks
            int c = it * 512 + tid;
            int row = c >> 2, blk = c & 3;
            int bg = blk ^ ((row >> 1) & 3);
            gld_lds16(Ak + (size_t)row * lda + bg * 8, As[b] + row * 32 + blk * 8);
        }
        {                                             // B: 128 rows x 4 blocks
            int row = tid >> 2, blk = tid & 3;
            int bg = blk ^ ((row >> 1) & 3);
            gld_lds16(Bk + (size_t)row * K + bg * 8, Bs[b] + row * 32 + blk * 8);
        }
    };

    const int NT = K >> 5;
    stage(0, 0);
    stage(1, 1);
    int rb = 0;
    for (int t = 0; t < NT; ++t) {
        if (t + 2 < NT) {
            stage(t + 2, rb ? rb - 1 : 2);   // (rb+2)%3: buffer retired at t-1
            asm volatile("s_waitcnt vmcnt(6)" ::: "memory");   // oldest 3 (= tile t) done
        } else if (t + 1 < NT) {
            asm volatile("s_waitcnt vmcnt(3)" ::: "memory");
        } else {
            asm volatile("s_waitcnt vmcnt(0)" ::: "memory");
        }
        __builtin_amdgcn_s_barrier();        // all waves' tile-t loads landed

        const u16* Ar = As[rb];
        const u16* Br = Bs[rb];
        bf16x8 af[4], bfv[4];
#pragma unroll
        for (int i = 0; i < 4; i++) af[i]  = *(const bf16x8*)(Ar + (wm + i * 16 + l16) * 32 + qsw);
#pragma unroll
        for (int j = 0; j < 4; j++) bfv[j] = *(const bf16x8*)(Br + (wn + j * 16 + l16) * 32 + qsw);
        __builtin_amdgcn_s_setprio(1);
#pragma unroll
        for (int i = 0; i < 4; i++)
#pragma unroll
            for (int j = 0; j < 4; j++)
                acc[i][j] = __builtin_amdgcn_mfma_f32_16x16x32_bf16(af[i], bfv[j], acc[i][j], 0, 0, 0);
        __builtin_amdgcn_s_setprio(0);
        __builtin_amdgcn_s_barrier();        // buf[rb] fully read -> may be restaged
        rb = (rb == 2) ? 0 : rb + 1;
    }

#pragma unroll
    for (int i = 0; i < 4; i++)
#pragma unroll
        for (int j = 0; j < 4; j++) {
            int mrow = m0 + wm + i * 16 + quad * 4;
            int ncol = n0 + wn + j * 16 + l16;
            if (BF16OUT) {
                u16* Cp = (u16*)Cv + (size_t)mrow * N + ncol;
                for (int rr = 0; rr < 4; rr++) Cp[(size_t)rr * N] = f2bf(acc[i][j][rr]);
            } else {
                float* Cp = (float*)Cv + (size_t)mrow * N + ncol;
                for (int rr = 0; rr < 4; rr++) Cp[(size_t)rr * N] = acc[i][j][rr];
            }
        }
}

// ---------------- fused build_q + k_rope from bf16 qkv ----------------
__global__ void build_qckv(const u16* __restrict__ qkv, const float* __restrict__ cosT,
                           const float* __restrict__ sinT, u16* __restrict__ qb,
                           u16* __restrict__ kropeb) {
    const float QS = 0.07216878364870323f * 1.4426950408889634f; // 1/sqrt(192) * log2(e)
    int idx = blockIdx.x * blockDim.x + threadIdx.x;
    const int NQTH = M_ * H_ * 96;
    if (idx < NQTH) {
        int p = idx % 96; int t = idx / 96; int h = t % H_; int row = t / H_;
        int l = row & (L_ - 1); int b = row >> 11;
        const u16* src = qkv + (size_t)row * QKVP_ + h * DQ_;
        u16* dst = qb + ((size_t)(b * H_ + h) * L_ + l) * DQ_;
        int d = 2 * p;
        uint32_t w = *(const uint32_t*)(src + d);
        float x1 = bf2f((u16)(w & 0xffff)), x2 = bf2f((u16)(w >> 16));
        uint32_t o;
        if (d < DH_) o = cvtpk(x1 * QS, x2 * QS);
        else {
            int i = (d - DH_) >> 1;
            float c = cosT[(size_t)l * 32 + i], s = sinT[(size_t)l * 32 + i];
            o = cvtpk((x1 * c - x2 * s) * QS, (x1 * s + x2 * c) * QS);
        }
        *(uint32_t*)(dst + d) = o;
    } else {
        idx -= NQTH;
        if (idx >= M_ * 32) return;
        int i = idx & 31; int row = idx >> 5;
        int l = row & (L_ - 1);
        uint32_t w = *(const uint32_t*)(qkv + (size_t)row * QKVP_ + NQ_ + RK_ + 2 * i);
        float x1 = bf2f((u16)(w & 0xffff)), x2 = bf2f((u16)(w >> 16));
        float c = cosT[(size_t)l * 32 + i], s = sinT[(size_t)l * 32 + i];
        *(uint32_t*)(kropeb + (size_t)row * RD_ + 2 * i) = cvtpk(x1 * c - x2 * s, x1 * s + x2 * c);
    }
}

// ---------------- build k (B,H,L,192) + vT (B,H,192,L perm) from bf16 up ----------------
__global__ __launch_bounds__(256) void build_kvt(const u16* __restrict__ up,
        const u16* __restrict__ kropeb, u16* __restrict__ kb, u16* __restrict__ vtb) {
    __shared__ u16 vt[64][193];
    int blk = blockIdx.x;          // (b*H+h)*32 + lt
    int lt = blk & 31; int bh = blk >> 5; int h = bh % H_; int b = bh / H_;
    int tid = threadIdx.x;
    int l0 = lt * 64;
    for (int it = 0; it < 48; ++it) {
        int idx = it * 256 + tid;  // 64*192
        int lr = idx / 192, d = idx % 192;
        size_t row = (size_t)b * L_ + l0 + lr;
        u16 vv = (d < DH_) ? up[row * NUP_ + h * 320 + DH_ + d]
                           : up[row * NUP_ + h * 320 + 2 * DH_ + (d - DH_)];
        vt[lr][d] = vv;
        u16 kbf = (d < DH_) ? up[row * NUP_ + h * 320 + d]
                            : kropeb[row * RD_ + (d - DH_)];
        kb[((size_t)bh * L_ + l0 + lr) * DQ_ + d] = kbf;
    }
    __syncthreads();
    for (int it = 0; it < 48; ++it) {
        int idx = it * 256 + tid;
        int lr = idx & 63, d = idx >> 6;
        int l = l0 + lr;
        int s5 = l & 31;
        int k5 = ((s5 >> 2) & 3) * 8 + ((s5 >> 4) & 1) * 4 + (s5 & 3);
        int lp = (l & ~31) | k5;
        vtb[((size_t)bh * DQ_ + d) * L_ + lp] = vt[lr][d];
    }
}

// ---------------- flash attention, causal, S^T, 1024 blocks x 512 threads ----------------
// 128 q-rows per block (halved state -> fits the 128-VGPR cap of (512,4), no spill;
// round 8's 2-block regression was accumulator spill at 200+ regs).
// Block (bh, tt, j): segs QT=15-tt then QT=tt (16 supertiles of 128 rows), quarter j
// of each QT's tile range [0, 2QT+1]: st in [(j*nt)/4, ((j+1)*nt)/4). Empty quarters
// write m=-inf / l=0 partials (merge weighs them to 0).
// LDS 72KB (K dbuf 2x24K + V single 24K) -> 2 blocks/CU with VGPR<=128.
__global__ __launch_bounds__(512, 4) void attn(const u16* __restrict__ qb,
        const u16* __restrict__ kb, const u16* __restrict__ vtb,
        u16* __restrict__ poA, u16* __restrict__ poS,
        float* __restrict__ pmB, float* __restrict__ plB) {
    __shared__ __align__(16) u16 Ks[2][64 * 192];
    __shared__ __align__(16) u16 Vs[192 * 64];
    int id = blockIdx.x;
    int bh = id & 31, tj = id >> 5;      // same-bh blocks share XCD (id%8 = bh%8)
    int tt = tj >> 2, j = tj & 3;
    int tid = threadIdx.x, wave = tid >> 6, lane = tid & 63;
    int quad = lane >> 4, l16 = lane & 15;

    // swizzle lane constants: row&7 == l16&7 for all fragment reads
    const int x7 = l16 & 7;
    const int h2 = (x7 >> 2) & 1;
    const int qx = quad ^ (x7 & 3);
    const int oA = h2 * 32 + qx * 8;        // even kk  / V g=0
    const int oB = (1 - h2) * 32 + qx * 8;  // odd  kk  / V g=1

    const size_t poSzE = (size_t)512 * 128 * 192;   // elements per split (25.2 MB)
    u16* po = (j == 0) ? poA : poS + (size_t)(j - 1) * poSzE;
    float* pm = pmB + (size_t)j * 65536;
    float* pl = plB + (size_t)j * 65536;

    const u16* kbase0 = kb + (size_t)bh * L_ * DQ_;
    const u16* vbase0 = vtb + (size_t)bh * (size_t)DQ_ * L_;
    floatx4 zero4 = {0.f, 0.f, 0.f, 0.f};

    auto stageK = [&](int st, int buf) {
        const u16* kg = kbase0 + (size_t)st * 64 * DQ_;
        u16* kd = &Ks[buf][0];
        for (int it = 0; it < 3; ++it) {
            int c = it * 512 + tid;          // 0..1535 = 64 rows * 24 blocks
            int s = c / 24, blk = c - s * 24;
            int blog = (blk & 24) | ((blk & 7) ^ (s & 7));
            gld_lds16(kg + (size_t)s * DQ_ + blog * 8, kd + c * 8);
        }
    };
    auto stageV = [&](int st) {
        const u16* vg = vbase0 + st * 64;
        for (int it = 0; it < 3; ++it) {
            int c = it * 512 + tid;          // 0..1535 = 192 rows * 8 blocks
            int d = c >> 3, blk = c & 7;
            int blog = blk ^ (d & 7);
            gld_lds16(vg + (size_t)d * L_ + blog * 8, Vs + c * 8);
        }
    };

    for (int seg = 0; seg < 2; ++seg) {
        const int QT = seg == 0 ? (15 - tt) : tt;
        const int nt = 2 * QT + 2;
        const int st0 = (j * nt) >> 2;
        const int stE = ((j + 1) * nt) >> 2;   // exclusive

        bf16x8 aq[6];
        const u16* qbase = qb + ((size_t)bh * L_ + QT * 128 + wave * 16 + l16) * DQ_;
#pragma unroll
        for (int kk = 0; kk < 6; kk++)
            aq[kk] = *(const bf16x8*)(qbase + kk * 32 + quad * 8);

        floatx4 o[12];
#pragma unroll
        for (int i = 0; i < 12; i++) o[i] = zero4;
        float m_i = -INFINITY;
        float l_i = 0.f;

        if (st0 < stE) {
            int cur = 0;
            stageK(st0, 0);                                     // prologue
            asm volatile("s_waitcnt vmcnt(0)" ::: "memory");
            __builtin_amdgcn_s_barrier();

            for (int st = st0; st < stE; ++st) {
                stageV(st);                                      // 3 loads (oldest)
                if (st + 1 < stE) stageK(st + 1, cur ^ 1);       // +3 loads
                const u16* Kc = &Ks[cur][0];

                // liveness: R multiple of 16; wave live iff R >= 0
                int R = QT * 128 + wave * 16 - st * 64;
                int smax = min(3, (R + 15) >> 4);
                bool live = smax >= 0;

                float pv[4][4];
                float mxa = -INFINITY;
#pragma unroll
                for (int stile = 0; stile < 4; ++stile) {
                    if (stile > smax) {
                        for (int r = 0; r < 4; r++) pv[stile][r] = 0.f;
                        continue;
                    }
                    floatx4 sv = zero4;
#pragma unroll
                    for (int kk = 0; kk < 6; kk++) {
                        int off = (kk >> 1) * 64 + ((kk & 1) ? oB : oA);
                        bf16x8 kf = *(const bf16x8*)(Kc + (stile * 16 + l16) * 192 + off);
                        sv = __builtin_amdgcn_mfma_f32_16x16x32_bf16(kf, aq[kk], sv, 0, 0, 0);
                    }
                    int sb = stile * 16;
                    if (sb + 15 > R) {
                        for (int r = 0; r < 4; r++) {
                            float v = (sb + quad * 4 + r > R + l16) ? -1e30f : sv[r];
                            pv[stile][r] = v; mxa = fmaxf(mxa, v);
                        }
                    } else {
                        for (int r = 0; r < 4; r++) { pv[stile][r] = sv[r]; mxa = fmaxf(mxa, sv[r]); }
                    }
                }

                bf16x8 pf[2];
                if (live) {
                    float mx = mxa;
                    mx = fmaxf(mx, __shfl_xor(mx, 16));
                    mx = fmaxf(mx, __shfl_xor(mx, 32));
                    float mn;
                    if (__all(mx <= m_i + 8.0f)) {
                        mn = m_i;                 // defer-max: keep stale max, no rescale
                    } else {
                        mn = fmaxf(m_i, mx);
                        float alpha = exp2f(m_i - mn);
                        m_i = mn;
                        l_i *= alpha;
                        for (int i = 0; i < 12; i++) o[i] *= alpha;
                    }
                    float rs = 0.f;
#pragma unroll
                    for (int stile = 0; stile < 4; ++stile) {
                        if (stile > smax) continue;
                        for (int r = 0; r < 4; r++) {
                            float e = exp2f(pv[stile][r] - mn);
                            pv[stile][r] = e;
                            rs += e;
                        }
                    }
                    rs += __shfl_xor(rs, 16);
                    rs += __shfl_xor(rs, 32);
                    l_i += rs;
                    for (int g = 0; g < 2; g++) {
                        union { bf16x8 v; u16 s[8]; } u;
                        for (int r = 0; r < 4; r++) {
                            u.s[r]     = f2bf(pv[g * 2][r]);
                            u.s[4 + r] = f2bf(pv[g * 2 + 1][r]);
                        }
                        pf[g] = u.v;
                    }
                }

                // V(st) landed: counted wait + barrier publishes to all waves
                if (st + 1 < stE) { asm volatile("s_waitcnt vmcnt(3)" ::: "memory"); }
                else              { asm volatile("s_waitcnt vmcnt(0)" ::: "memory"); }
                __builtin_amdgcn_s_barrier();

                if (live) {
                    for (int g = 0; g < 2; g++) {
                        int vo = g ? oB : oA;
#pragma unroll
                        for (int dtile = 0; dtile < 12; dtile++) {
                            bf16x8 vf = *(const bf16x8*)(Vs + (dtile * 16 + l16) * 64 + vo);
                            o[dtile] = __builtin_amdgcn_mfma_f32_16x16x32_bf16(vf, pf[g], o[dtile], 0, 0, 0);
                        }
                    }
                }
                asm volatile("s_waitcnt vmcnt(0)" ::: "memory");   // K(st+1) landed
                __builtin_amdgcn_s_barrier();                      // Vs/Ks WAR + K publish
                cur ^= 1;
            }
        }

        // write partials: po[tile][q 128][d 192] bf16, pm/pl[tile][q 128]
        int tile = bh * 16 + QT;
        int q = wave * 16 + l16;
        u16* dst = po + ((size_t)tile * 128 + q) * 192;
        for (int dtile = 0; dtile < 12; dtile++) {
            ushort4 pk;
            pk.x = f2bf(o[dtile][0]);
            pk.y = f2bf(o[dtile][1]);
            pk.z = f2bf(o[dtile][2]);
            pk.w = f2bf(o[dtile][3]);
            *(ushort4*)(dst + dtile * 16 + quad * 4) = pk;
        }
        if (quad == 0) {
            pm[(size_t)tile * 128 + q] = m_i;
            pl[(size_t)tile * 128 + q] = l_i;
        }
        __syncthreads();
    }
}

// ---------------- merge the four split-s quarters -> ao (B,L,H,192) bf16 ----------------
__global__ void attn_merge(const u16* __restrict__ poA, const u16* __restrict__ poS,
                           const float* __restrict__ pmB, const float* __restrict__ plB,
                           u16* __restrict__ ao) {
    int idx = blockIdx.x * blockDim.x + threadIdx.x;   // 512*128*48
    int c = idx % 48; int rest = idx / 48;
    int q = rest & 127; int tile = rest >> 7;
    int bh = tile >> 4, QT = tile & 15;
    size_t mi = (size_t)tile * 128 + q;
    const size_t poSzE = (size_t)512 * 128 * 192;
    float mj[4], lj[4];
    float m = -INFINITY;
    for (int jj = 0; jj < 4; jj++) {
        mj[jj] = pmB[(size_t)jj * 65536 + mi];
        lj[jj] = plB[(size_t)jj * 65536 + mi];
        m = fmaxf(m, mj[jj]);
    }
    float aj[4], denom = 0.f;
    for (int jj = 0; jj < 4; jj++) { aj[jj] = exp2f(mj[jj] - m); denom += lj[jj] * aj[jj]; }
    float inv = 1.0f / denom;
    float acc0 = 0.f, acc1 = 0.f, acc2 = 0.f, acc3 = 0.f;
    for (int jj = 0; jj < 4; jj++) {
        const u16* pj = (jj == 0) ? poA : poS + (size_t)(jj - 1) * poSzE;
        ushort4 u0 = *(const ushort4*)(pj + mi * 192 + c * 4);
        float s = aj[jj] * inv;
        acc0 += bf2f(u0.x) * s; acc1 += bf2f(u0.y) * s;
        acc2 += bf2f(u0.z) * s; acc3 += bf2f(u0.w) * s;
    }
    int b = bh >> 4, h = bh & 15;
    int l = QT * 128 + q;
    u16* dst = ao + (((size_t)(b * L_ + l)) * H_ + h) * DQ_ + c * 4;
    uint2 pk2;
    pk2.x = cvtpk(acc0, acc1);
    pk2.y = cvtpk(acc2, acc3);
    *(uint2*)dst = pk2;
}

extern "C" void kernel_launch(void* const* d_in, const int* in_sizes, int n_in,
                              void* d_out, int out_size, void* d_ws, size_t ws_size,
                              hipStream_t stream) {
    const float* x    = (const float*)d_in[0];
    const float* cosT = (const float*)d_in[1];
    const float* sinT = (const float*)d_in[2];
    const float* wq   = (const float*)d_in[3];
    const float* wkv  = (const float*)d_in[4];
    const float* wup  = (const float*)d_in[5];
    const float* wout = (const float*)d_in[6];
    float* out = (float*)d_out;
    char* ws = (char*)d_ws;

    size_t off = 0;
    auto alloc = [&](size_t b) { size_t r = off; off += (b + 255) & ~(size_t)255; return r; };
    u16* xb     = (u16*)(ws + alloc((size_t)M_ * E_ * 2));      // 16.78 MB  (dead after qkv GEMM)
    u16* wqkvT  = (u16*)(ws + alloc((size_t)QKVP_ * E_ * 2));   // 15.73 MB  (dead after qkv GEMM)
    u16* wupT   = (u16*)(ws + alloc((size_t)NUP_ * RK_ * 2));
    u16* woutT  = (u16*)(ws + alloc((size_t)E_ * NQ_ * 2));
    u16* qb     = (u16*)(ws + alloc((size_t)B_ * H_ * L_ * DQ_ * 2));
    u16* kb     = (u16*)(ws + alloc((size_t)B_ * H_ * L_ * DQ_ * 2));
    u16* vtb    = (u16*)(ws + alloc((size_t)B_ * H_ * DQ_ * L_ * 2));
    u16* ao     = (u16*)(ws + alloc((size_t)M_ * NQ_ * 2));
    u16* kropeb = (u16*)(ws + alloc((size_t)M_ * RD_ * 2));
    char* scratch = ws + alloc((size_t)M_ * NUP_ * 4);   // 83.9 MB union region
    // phase 1: bf16 intermediates qkvb [M x 3840] then upb [M x 5120] (no alias)
    u16* qkvb = (u16*)(scratch);                                  // 31.5 MB
    size_t qkvSz = ((size_t)M_ * QKVP_ * 2 + 255) & ~(size_t)255;
    u16* upb  = (u16*)(scratch + qkvSz);                          // 41.9 MB (total 73.4 < 83.9)
    // phase 2 (attn): 4 partial buffers. po j=0 overlays dead xb+wqkvT (25.2 <= 32.5 MB);
    // j=1..3 + pm/pl in scratch: 3*25.2 + 2.0 = 77.6 MB <= 83.9.
    size_t poSz = (size_t)512 * 128 * 192 * 2;                    // 25.2 MB
    u16*   poA = (u16*)(ws);
    u16*   poS = (u16*)(scratch);
    float* pmB = (float*)(scratch + 3 * poSz);                    // [4][65536]
    float* plB = (float*)(scratch + 3 * poSz + 4 * 65536 * 4);

    dim3 tb(32, 8);
    int n4 = M_ * E_ / 4;
    convert_bf16<<<(n4 + 255) / 256, 256, 0, stream>>>(x, xb, n4);
    transpose_all<<<16384, tb, 0, stream>>>(wq, wkv, wup, wout, wqkvT, wupT, woutT);

    // fused q+kv projection: 256x128 GEMM, bf16 out, grid 30x16 = 480 blocks
    gemm256<true><<<dim3(QKVP_ / 128, M_ / 256), 512, 0, stream>>>(xb, wqkvT, qkvb, M_, QKVP_, E_, E_);

    int nb = (M_ * H_ * 96 + M_ * 32 + 255) / 256;
    build_qckv<<<nb, 256, 0, stream>>>(qkvb, cosT, sinT, qb, kropeb);

    // up-projection: A = qkvb cols 3072..3583 (lda=3840), bf16 out, grid 40x16
    gemm256<true><<<dim3(NUP_ / 128, M_ / 256), 512, 0, stream>>>(qkvb + NQ_, wupT, upb, M_, NUP_, RK_, QKVP_);
    build_kvt<<<B_ * H_ * 32, 256, 0, stream>>>(upb, kropeb, kb, vtb);

    attn<<<1024, 512, 0, stream>>>(qb, kb, vtb, poA, poS, pmB, plB);
    attn_merge<<<(512 * 128 * 48) / 256, 256, 0, stream>>>(poA, poS, pmB, plB, ao);

    // output projection: 256x128 GEMM, fp32 out, grid 16x16 = 256 blocks
    gemm256<false><<<dim3(E_ / 128, M_ / 256), 512, 0, stream>>>(ao, woutT, out, M_, E_, NQ_, NQ_);
}